// Round 3
// baseline (243.600 us; speedup 1.0000x reference)
//
#include <hip/hip_runtime.h>

#define NN 30000
#define NE 120000
#define WD 32

__global__ void k_zero_cnt(int* __restrict__ cnt) {
  int n = blockIdx.x * 256 + threadIdx.x;
  if (n < NN) cnt[n] = 0;
}

// kh[e,:] = relu(edge_attr @ k_w1 + k_b1); cnt[dst[e]]++
__global__ void k_prep(const float* __restrict__ ea, const float* __restrict__ w1,
                       const float* __restrict__ b1, const int* __restrict__ dst,
                       float* __restrict__ kh, int* __restrict__ cnt) {
  int e = blockIdx.x * 256 + threadIdx.x;
  if (e >= NE) return;
  float a[6];
#pragma unroll
  for (int i = 0; i < 6; i++) a[i] = ea[e * 6 + i];
#pragma unroll
  for (int k = 0; k < 8; k++) {
    float s = b1[k];
#pragma unroll
    for (int i = 0; i < 6; i++) s = fmaf(a[i], w1[i * 8 + k], s);
    kh[e * 8 + k] = fmaxf(s, 0.f);
  }
  atomicAdd(&cnt[dst[e]], 1);
}

__device__ __forceinline__ unsigned short f2b(float f) {
  unsigned u = __float_as_uint(f);
  unsigned r = (u + 0x7fff + ((u >> 16) & 1)) >> 16;  // round-to-nearest-even
  return (unsigned short)r;
}

// Node transform. 32 nodes/block. h staged in LDS; weights in LDS transposed
// [k][o][i] with XOR swizzle for conflict-free ds_read_b128. Node-pairs share
// weight reads. Outputs: Pb[n][k][o] bf16 (k=0..8), Pr[n][o] f32 (root term).
// Also zeroes agg[n,:].
template <bool FIRST>
__global__ void k_node(const float* __restrict__ x, const float* __restrict__ fc1w,
                       const float* __restrict__ fc1b, const int* __restrict__ cnt,
                       const float* __restrict__ cbias, const float* __restrict__ kw2,
                       const float* __restrict__ kb2, const float* __restrict__ root,
                       float* __restrict__ agg, unsigned short* __restrict__ Pb,
                       float* __restrict__ Pr) {
  __shared__ float Wl[10 * 1024];
  __shared__ float hL[32 * WD];
  int tid = threadIdx.x;
  // stage weights, transposed+swizzled: element (k,i,o) -> (k*1024+o*32+i)^((o&7)<<2)
  for (int f = tid; f < 10 * 1024; f += 256) {
    int k = f >> 10, i = (f >> 5) & 31, o = f & 31;
    float v;
    if (f < 8192) v = kw2[f];
    else if (f < 9216) v = kb2[f - 8192];
    else v = root[f - 9216];
    Wl[(k * 1024 + o * 32 + i) ^ ((o & 7) << 2)] = v;
  }
  int base = blockIdx.x * 32;
  // stage h for this block's 32 nodes; zero agg
  for (int e = tid; e < 32 * WD; e += 256) {
    int ln = e >> 5, o = e & 31;
    int n = base + ln;
    float h = 0.f;
    if (n < NN) {
      if (FIRST) {
        h = fmaf(x[n], fc1w[o], fc1b[o]);
      } else {
        float ic = 1.0f / (float)max(cnt[n], 1);
        h = fmaxf(fmaf(agg[n * WD + o], ic, Pr[n * WD + o] + cbias[o]), 0.f);
      }
      agg[n * WD + o] = 0.f;  // pre-zero for the upcoming edge scatter
    }
    hL[e] = h;
  }
  __syncthreads();
  int g = tid >> 5, o = tid & 31;
  int sw = (o & 7) << 2;
#pragma unroll
  for (int p = 0; p < 2; p++) {
    int ln0 = p * 16 + g, ln1 = ln0 + 8;
    float4 hv0[8], hv1[8];
#pragma unroll
    for (int c = 0; c < 8; c++) {
      hv0[c] = *(const float4*)&hL[ln0 * WD + c * 4];  // broadcast reads
      hv1[c] = *(const float4*)&hL[ln1 * WD + c * 4];
    }
    int n0 = base + ln0, n1 = base + ln1;
#pragma unroll
    for (int k = 0; k < 10; k++) {
      float a0 = 0.f, a1 = 0.f;
#pragma unroll
      for (int c = 0; c < 8; c++) {
        float4 w = *(const float4*)&Wl[k * 1024 + o * 32 + (((c << 2) ^ sw))];
        a0 = fmaf(hv0[c].x, w.x, a0); a1 = fmaf(hv1[c].x, w.x, a1);
        a0 = fmaf(hv0[c].y, w.y, a0); a1 = fmaf(hv1[c].y, w.y, a1);
        a0 = fmaf(hv0[c].z, w.z, a0); a1 = fmaf(hv1[c].z, w.z, a1);
        a0 = fmaf(hv0[c].w, w.w, a0); a1 = fmaf(hv1[c].w, w.w, a1);
      }
      if (k < 9) {
        if (n0 < NN) Pb[(size_t)(n0 * 9 + k) * WD + o] = f2b(a0);
        if (n1 < NN) Pb[(size_t)(n1 * 9 + k) * WD + o] = f2b(a1);
      } else {
        if (n0 < NN) Pr[n0 * WD + o] = a0;
        if (n1 < NN) Pr[n1 * WD + o] = a1;
      }
    }
  }
}

// per edge (16 lanes, 2 outputs/lane): msg = Pb[s,8,:] + sum_k kh[e,k]*Pb[s,k,:]
__global__ void k_edge(const unsigned int* __restrict__ Pb32,
                       const float* __restrict__ kh, const int* __restrict__ src,
                       const int* __restrict__ dst, float* __restrict__ agg) {
  int t = blockIdx.x * 256 + threadIdx.x;
  int e = t >> 4;
  int u = t & 15;
  int s = src[e], d = dst[e];
  float kv = (u < 8) ? kh[e * 8 + u] : 0.f;
  const unsigned int* Ps = Pb32 + (size_t)s * 144;  // 9*32 bf16 = 144 uints
  unsigned int b = Ps[8 * 16 + u];
  float m0 = __uint_as_float(b << 16);
  float m1 = __uint_as_float(b & 0xffff0000u);
#pragma unroll
  for (int k = 0; k < 8; k++) {
    float kk = __shfl(kv, k, 16);
    unsigned int w = Ps[k * 16 + u];
    m0 = fmaf(kk, __uint_as_float(w << 16), m0);
    m1 = fmaf(kk, __uint_as_float(w & 0xffff0000u), m1);
  }
  atomicAdd(&agg[d * WD + 2 * u], m0);
  atomicAdd(&agg[d * WD + 2 * u + 1], m1);
}

// final: h4 = relu(agg/cnt + Pr + cbias); out[n] = h4 @ fc2w + fc2b
__global__ void k_out(const float* __restrict__ agg, const int* __restrict__ cnt,
                      const float* __restrict__ Pr, const float* __restrict__ cbias,
                      const float* __restrict__ fc2w, const float* __restrict__ fc2b,
                      float* __restrict__ out) {
  int t = blockIdx.x * 256 + threadIdx.x;
  int n = t >> 5, o = t & 31;
  if (n >= NN) return;
  float ic = 1.0f / (float)max(cnt[n], 1);
  float h = fmaxf(fmaf(agg[t], ic, Pr[t] + cbias[o]), 0.f);
  float s = h * fc2w[o];
#pragma unroll
  for (int d = 16; d; d >>= 1) s += __shfl_xor(s, d, 32);
  if (o == 0) out[n] = s + fc2b[0];
}

extern "C" void kernel_launch(void* const* d_in, const int* in_sizes, int n_in,
                              void* d_out, int out_size, void* d_ws, size_t ws_size,
                              hipStream_t stream) {
  const float* x     = (const float*)d_in[0];
  const int*   ei    = (const int*)d_in[1];
  const float* ea    = (const float*)d_in[2];
  const float* fc1w  = (const float*)d_in[3];
  const float* fc1b  = (const float*)d_in[4];
  const float* kw1   = (const float*)d_in[5];
  const float* kb1   = (const float*)d_in[6];
  const float* kw2   = (const float*)d_in[7];
  const float* kb2   = (const float*)d_in[8];
  const float* root  = (const float*)d_in[9];
  const float* cbias = (const float*)d_in[10];
  const float* fc2w  = (const float*)d_in[11];
  const float* fc2b  = (const float*)d_in[12];
  float* out = (float*)d_out;

  float* ws  = (float*)d_ws;
  float* kh  = ws;                          // NE*8
  float* Pr  = kh + NE * 8;                 // NN*WD
  float* agg = Pr + NN * WD;                // NN*WD
  int*   cnt = (int*)(agg + NN * WD);       // NN
  unsigned short* Pb = (unsigned short*)(cnt + NN);  // NN*9*WD bf16
  unsigned int* Pb32 = (unsigned int*)Pb;

  const int* srcp = ei;       // edge_index[0]
  const int* dstp = ei + NE;  // edge_index[1]

  k_zero_cnt<<<(NN + 255) / 256, 256, 0, stream>>>(cnt);
  k_prep<<<(NE + 255) / 256, 256, 0, stream>>>(ea, kw1, kb1, dstp, kh, cnt);

  const int node_grid = (NN + 31) / 32;
  for (int l = 0; l < 4; l++) {
    if (l == 0)
      k_node<true><<<node_grid, 256, 0, stream>>>(x, fc1w, fc1b, cnt, cbias, kw2,
                                                  kb2, root, agg, Pb, Pr);
    else
      k_node<false><<<node_grid, 256, 0, stream>>>(x, fc1w, fc1b, cnt, cbias, kw2,
                                                   kb2, root, agg, Pb, Pr);
    k_edge<<<NE * 16 / 256, 256, 0, stream>>>(Pb32, kh, srcp, dstp, agg);
  }
  k_out<<<(NN * WD + 255) / 256, 256, 0, stream>>>(agg, cnt, Pr, cbias, fc2w, fc2b, out);
}